// Round 1
// baseline (260.149 us; speedup 1.0000x reference)
//
#include <hip/hip_runtime.h>

// SparseMaxPool, two-phase: (A) blanket zero-fill at fillBuffer rate,
// (B) overwrite only the ~2548 valid sparse entries per slice.
// Valid offsets o=c-r: 0..15 (any r), odd 17..31 (r%2==0),
// o%4==3 in 35..63 (r%4==0), o%8==7 in 71..127 (r%8==0).
// Window max via LDS doubling table: levels k=0..7 concatenated,
// level-k base = 129*k - (2^k - 1), len = 129 - 2^k (777 floats total).

#define NN 128
#define SLICE_ELEMS (NN * NN)

__device__ __forceinline__ void win_params(int o, int& lb, int& d2) {
    int w = o + 1;                 // window length
    int k = 31 - __clz(w);         // floor(log2(w)), w>=1
    int p2 = 1 << k;
    lb = 129 * k - (p2 - 1);       // level-k base (0,128,255,380,501,614,711,776)
    d2 = w - p2;                   // second-read offset
}

__global__ __launch_bounds__(256) void sparse_maxpool_kernel(
        const float* __restrict__ x, float* __restrict__ out) {
    __shared__ float buf[784];     // 777 used
    const int tid = threadIdx.x;
    const int slice = blockIdx.x;  // b*256 + d, 4096 total
    float* __restrict__ out_s = out + (size_t)slice * SLICE_ELEMS;

    // Issue x -> LDS level-0 load first; its latency hides under the zero blast.
    if (tid < NN) buf[tid] = x[(size_t)slice * NN + tid];

    // ---- Phase A: blanket zero-fill, pure coalesced float4 stores ----
    float4 z = make_float4(0.f, 0.f, 0.f, 0.f);
    float4* __restrict__ o4 = reinterpret_cast<float4*>(out_s);
    #pragma unroll
    for (int it = 0; it < 16; ++it)
        o4[it * 256 + tid] = z;

    // ---- Build doubling table levels 1..7 ----
    // Each __syncthreads() drains vmcnt(0) first, so by the end of this loop
    // every phase-A zero store is complete: phase-B overwrites are ordered.
    __syncthreads();
    int base_prev = 0, base_cur = NN;
    #pragma unroll
    for (int k = 1; k <= 7; ++k) {
        int half = 1 << (k - 1);
        int len = (NN + 1) - (1 << k);
        if (tid < len)
            buf[base_cur + tid] = fmaxf(buf[base_prev + tid], buf[base_prev + tid + half]);
        __syncthreads();
        base_prev = base_cur;
        base_cur += len;
    }

    // ---- Phase B: sparse overwrites (out[r,c] at flat index r*129 + o) ----
    // Group 1: o = 0..15, every row. 16 offsets x 128 rows / 256 thr = 8 iters.
    {
        int o = tid & 15, lb, d2;
        win_params(o, lb, d2);
        int r0 = tid >> 4;                       // 0..15
        #pragma unroll
        for (int jj = 0; jj < 8; ++jj) {
            int r = r0 + 16 * jj;                // covers 0..127
            if (r + o < NN)
                out_s[r * 129 + o] = fmaxf(buf[lb + r], buf[lb + r + d2]);
        }
    }
    // Group 2: o = 17,19,..,31 (8 offsets), r even. 8 x 64 / 256 = 2 iters.
    {
        int o = 17 + 2 * (tid & 7), lb, d2;
        win_params(o, lb, d2);
        int r0 = 2 * (tid >> 3);                 // 0..62 even
        #pragma unroll
        for (int jj = 0; jj < 2; ++jj) {
            int r = r0 + 64 * jj;                // covers even 0..126
            if (r + o < NN)
                out_s[r * 129 + o] = fmaxf(buf[lb + r], buf[lb + r + d2]);
        }
    }
    // Group 3: o = 35,39,..,63 (8 offsets), r%4==0. One iter.
    {
        int o = 35 + 4 * (tid & 7), lb, d2;
        win_params(o, lb, d2);
        int r = 4 * (tid >> 3);                  // 0..124 step 4
        if (r + o < NN)
            out_s[r * 129 + o] = fmaxf(buf[lb + r], buf[lb + r + d2]);
    }
    // Group 4: o = 71,79,..,127 (8 offsets), r%8==0. One iter.
    {
        int o = 71 + 8 * (tid & 7), lb, d2;
        win_params(o, lb, d2);
        int r = 8 * (tid >> 3);                  // 0..248 step 8 (valid r <= 56)
        if (r + o < NN)
            out_s[r * 129 + o] = fmaxf(buf[lb + r], buf[lb + r + d2]);
    }
}

extern "C" void kernel_launch(void* const* d_in, const int* in_sizes, int n_in,
                              void* d_out, int out_size, void* d_ws, size_t ws_size,
                              hipStream_t stream) {
    const float* x = (const float*)d_in[0];
    float* out = (float*)d_out;
    const int slices = in_sizes[0] / NN;   // 16*256 = 4096
    sparse_maxpool_kernel<<<dim3(slices), dim3(256), 0, stream>>>(x, out);
}